// Round 2
// 2326.738 us; speedup vs baseline: 3.9662x; 3.9662x over previous
//
#include <hip/hip_runtime.h>
#include <cmath>

#define NLEV 16
#define TBLSZ 524288
#define TMASK 524287u
#define STR 66           // LDS row stride in u32; (66 mod 32)=2 -> all tile patterns <=2-way (free)
#define ROWS 291         // max activation rows (fine MLP input)
#define NPB 64           // points per block

typedef short short8 __attribute__((ext_vector_type(8)));
typedef float f32x4 __attribute__((ext_vector_type(4)));
typedef unsigned int u32;
typedef unsigned short u16;

struct EncParams { int res[NLEV]; unsigned dense_mask; };

__device__ __host__ __forceinline__ u32 bf16_rtne_bits(float x) {
  union { float f; u32 u; } c; c.f = x;
  return (c.u + 0x7fffu + ((c.u >> 16) & 1u)) >> 16;
}

__device__ __forceinline__ float softplus100(float x) {
  float t = 100.0f * x;
  return (fmaxf(t, 0.0f) + log1pf(expf(-fabsf(t)))) * 0.01f;
}

// pack fp32 -> (hi bf16) | (lo bf16 << 16), hi+lo ~= x to ~2^-17 rel.
__device__ __forceinline__ u32 pack_hl(float x) {
  u32 hi = bf16_rtne_bits(x);
  float r = x - __uint_as_float(hi << 16);
  u32 lo = bf16_rtne_bits(r);
  return hi | (lo << 16);
}

struct AF { short8 h, l; };

// Load A-fragments (activations) for all K-tiles of a layer from packed LDS.
// lane l supplies A[row = l&15][k = kq + e] per MFMA; p = point column in LDS.
template<int KT, int IN>
__device__ __forceinline__ void load_a(const u32* hb, int p, int kq, AF* af) {
  #pragma unroll
  for (int t = 0; t < KT; ++t) {
    u32 pk[8];
    const bool tail = ((t + 1) * 32 > IN);   // compile-time after unroll
    #pragma unroll
    for (int e = 0; e < 8; ++e) {
      const int k = t * 32 + kq + e;
      if (tail) {
        const int row = (k < IN) ? k : (IN - 1);     // stay in-bounds
        const u32 v = hb[row * STR + p];
        pk[e] = (k < IN) ? v : 0u;                   // NaN-guard padding lanes
      } else {
        pk[e] = hb[k * STR + p];
      }
    }
    union { u32 u[4]; short8 v; } ch, cl;
    #pragma unroll
    for (int q = 0; q < 4; ++q) {
      ch.u[q] = __builtin_amdgcn_perm(pk[2 * q + 1], pk[2 * q], 0x05040100u); // low16s
      cl.u[q] = __builtin_amdgcn_perm(pk[2 * q + 1], pk[2 * q], 0x07060302u); // high16s
    }
    af[t].h = ch.v;
    af[t].l = cl.v;
  }
}

// One MLP layer: M=16 (wave's points) x N=NT*16 x K=KT*32, split-bf16 (3 MFMA/tile).
// Weight fragments: fragment (n*KT+t) is 2048B: 64 lanes x 32B [hi bf16x8 | lo bf16x8].
template<int KT, int NT, int IN, class Post>
__device__ __forceinline__ void layer(const u32* __restrict__ hb,
                                      const u16* __restrict__ wf,
                                      const float* __restrict__ bias,
                                      int p, int kq, int l, Post&& post) {
  AF af[KT];
  load_a<KT, IN>(hb, p, kq, af);
  __syncthreads();                         // everyone's A in regs -> LDS rows writable
  const short8* __restrict__ wp0 = ((const short8*)wf) + (l << 1);
  #pragma unroll 2
  for (int n = 0; n < NT; ++n) {
    const int j = n * 16 + (l & 15);
    const float bv = bias[j];
    f32x4 acc = {bv, bv, bv, bv};
    const short8* wp = wp0 + (size_t)(n * KT) * 128;
    #pragma unroll
    for (int t = 0; t < KT; ++t) {
      const short8 bh = wp[t * 128];
      const short8 bl = wp[t * 128 + 1];
      acc = __builtin_amdgcn_mfma_f32_16x16x32_bf16(af[t].h, bh, acc, 0, 0, 0);
      acc = __builtin_amdgcn_mfma_f32_16x16x32_bf16(af[t].h, bl, acc, 0, 0, 0);
      acc = __builtin_amdgcn_mfma_f32_16x16x32_bf16(af[t].l, bh, acc, 0, 0, 0);
    }
    post(n, j, acc);
  }
}

// ---------------- weight prep: fp32 [O x K] -> hi/lo bf16 B-fragments ----------------
__global__ __launch_bounds__(256)
void prep_weights(const float* __restrict__ s0, const float* __restrict__ s1,
                  const float* __restrict__ s2, const float* __restrict__ s3,
                  const float* __restrict__ s4, const float* __restrict__ s5,
                  u16* __restrict__ ws) {
  const int O[6]   = {256, 256, 257, 256, 256, 257};
  const int K[6]   = {35, 256, 256, 291, 256, 256};
  const int KT[6]  = {2, 8, 8, 10, 8, 8};
  const int NE[6]  = {16384, 65536, 69632, 81920, 65536, 69632};     // Opad*Kpad elements
  const int OFF[6] = {0, 32768, 163840, 303104, 466944, 598016};     // u16 offsets (2*NE cum.)
  const float* S[6] = {s0, s1, s2, s3, s4, s5};
  int t = blockIdx.x * 256 + threadIdx.x;
  #pragma unroll
  for (int L = 0; L < 6; ++L) {
    if (t < NE[L]) {
      const int e = t & 7, lane = (t >> 3) & 63, f = t >> 9;
      const int kt = f % KT[L], nt = f / KT[L];
      const int j = nt * 16 + (lane & 15);
      const int k = kt * 32 + ((lane >> 4) << 3) + e;
      const float v = (j < O[L] && k < K[L]) ? S[L][(size_t)j * K[L] + k] : 0.0f;
      const u32 hi = bf16_rtne_bits(v);
      const float r = v - __uint_as_float(hi << 16);
      const u32 lo = bf16_rtne_bits(r);
      // FIX (R1): fragment stride 1024 u16, lane stride 16 u16 (matches consumer's
      // wp0 = (short8*)wf + (l<<1); wp[t*128]). Previous version dropped the lane
      // term -> all 64 lanes raced into one slot -> garbage weights, absmax 0.52.
      u16* d = ws + OFF[L] + (size_t)f * 1024 + (size_t)lane * 16;
      d[e] = (u16)hi;
      d[8 + e] = (u16)lo;
      return;
    }
    t -= NE[L];
  }
}

// ---------------- fused kernel ----------------
__global__ __launch_bounds__(256, 2)
void fused_ingp(const float* __restrict__ x,
                const float* __restrict__ ctab, const float* __restrict__ cb0,
                const float* __restrict__ cb1, const float* __restrict__ cb2,
                const float* __restrict__ ftab, const float* __restrict__ fb0,
                const float* __restrict__ fb1, const float* __restrict__ fb2,
                const u16* __restrict__ cW0p, const u16* __restrict__ cW1p,
                const u16* __restrict__ cW2p, const u16* __restrict__ fW0p,
                const u16* __restrict__ fW1p, const u16* __restrict__ fW2p,
                float* __restrict__ out, EncParams ep) {
  __shared__ u32 hb[ROWS * STR];           // packed hi/lo bf16 activations (u32 each)
  const int tid = threadIdx.x;
  const int l = tid & 63;
  const int g = __builtin_amdgcn_readfirstlane(tid >> 6); // wave id = M-tile
  const int pbase = blockIdx.x * NPB;
  const int pt = pbase + l;
  const int p = g * 16 + (l & 15);          // A-read point column
  const int kq = (l >> 4) << 3;             // k-group within tile
  const int colb = g * 16 + ((l >> 4) << 2);// D-write point column base

  // ------------- hash encode: 4 levels per wave, both tables share idx/weights -------------
  const float* xp = x + (size_t)3 * pt;
  const float x0 = xp[0], x1 = xp[1], x2 = xp[2];
  const float q0 = fminf(fmaxf((x0 / 1.5f + 1.0f) * 0.5f, 0.0f), 1.0f);
  const float q1 = fminf(fmaxf((x1 / 1.5f + 1.0f) * 0.5f, 0.0f), 1.0f);
  const float q2 = fminf(fmaxf((x2 / 1.5f + 1.0f) * 0.5f, 0.0f), 1.0f);

  if (g == 0) {
    const u32 px0 = pack_hl(x0), px1 = pack_hl(x1), px2 = pack_hl(x2);
    hb[0 * STR + l] = px0; hb[1 * STR + l] = px1; hb[2 * STR + l] = px2;
    hb[288 * STR + l] = px0; hb[289 * STR + l] = px1; hb[290 * STR + l] = px2;
  }

  #pragma unroll
  for (int il = 0; il < 4; ++il) {
    const int lv = g * 4 + il;
    const int res = ep.res[lv];
    const bool dense = (ep.dense_mask >> lv) & 1;
    const float rf = (float)(res - 1);
    const float px = q0 * rf, py = q1 * rf, pz = q2 * rf;
    const int ix = (int)floorf(px), iy = (int)floorf(py), iz = (int)floorf(pz);
    const float wx = px - (float)ix, wy = py - (float)iy, wz = pz - (float)iz;
    float ca0 = 0.f, ca1 = 0.f, fa0 = 0.f, fa1 = 0.f;
    const float* ct = ctab + (size_t)lv * TBLSZ * 2;
    const float* ft = ftab + (size_t)lv * TBLSZ * 2;
    #pragma unroll
    for (int c = 0; c < 8; ++c) {
      const int ox = c & 1, oy = (c >> 1) & 1, oz = (c >> 2) & 1;
      const int cx = min(ix + ox, res), cy = min(iy + oy, res), cz = min(iz + oz, res);
      unsigned idx;
      if (dense) idx = (unsigned)(cx + (res + 1) * (cy + (res + 1) * cz));
      else idx = (((unsigned)cx) ^ ((unsigned)cy * 2654435761u) ^ ((unsigned)cz * 805459861u)) & TMASK;
      const float wc = (ox ? wx : 1.0f - wx) * (oy ? wy : 1.0f - wy) * (oz ? wz : 1.0f - wz);
      const float2 cv = *(const float2*)(ct + (size_t)idx * 2);
      const float2 fv = *(const float2*)(ft + (size_t)idx * 2);
      ca0 = fmaf(wc, cv.x, ca0); ca1 = fmaf(wc, cv.y, ca1);
      fa0 = fmaf(wc, fv.x, fa0); fa1 = fmaf(wc, fv.y, fa1);
    }
    hb[(3 + 2 * lv) * STR + l] = pack_hl(ca0);    // c_feat -> rows 3..34
    hb[(4 + 2 * lv) * STR + l] = pack_hl(ca1);
    hb[(256 + 2 * lv) * STR + l] = pack_hl(fa0);  // f_feat stash rows 256..287
    hb[(257 + 2 * lv) * STR + l] = pack_hl(fa1);
  }
  __syncthreads();

  auto post_act = [&](int n, int j, f32x4 a) {
    (void)n;
    #pragma unroll
    for (int r = 0; r < 4; ++r)
      hb[j * STR + colb + r] = pack_hl(softplus100(a[r]));
  };

  // ---------------- coarse MLP ----------------
  layer<2, 16, 35>(hb, cW0p, cb0, p, kq, l, post_act);
  __syncthreads();
  layer<8, 16, 256>(hb, cW1p, cb1, p, kq, l, post_act);
  __syncthreads();

  f32x4 ck[17];
  {
    AF af[8];
    load_a<8, 256>(hb, p, kq, af);
    __syncthreads();
    // stash copy-down: rows 288..290 -> 0..2 (x), 256..287 -> 3..34 (f_feat)
    for (int r = g; r < 35; r += 4) {
      const int src = (r < 3) ? (288 + r) : (253 + r);
      hb[r * STR + l] = hb[src * STR + l];
    }
    __syncthreads();
    const short8* __restrict__ wp0 = ((const short8*)cW2p) + (l << 1);
    #pragma unroll
    for (int n = 0; n < 17; ++n) {
      const int j = n * 16 + (l & 15);
      const float bv = (j < 257) ? cb2[j] : 0.0f;
      f32x4 a = {bv, bv, bv, bv};
      const short8* wp = wp0 + (size_t)(n * 8) * 128;
      #pragma unroll
      for (int t = 0; t < 8; ++t) {
        const short8 bh = wp[t * 128];
        const short8 bl = wp[t * 128 + 1];
        a = __builtin_amdgcn_mfma_f32_16x16x32_bf16(af[t].h, bh, a, 0, 0, 0);
        a = __builtin_amdgcn_mfma_f32_16x16x32_bf16(af[t].h, bl, a, 0, 0, 0);
        a = __builtin_amdgcn_mfma_f32_16x16x32_bf16(af[t].l, bh, a, 0, 0, 0);
      }
      ck[n] = a;                              // full c_out kept for final sum
      if (j >= 1 && j <= 256) {               // c_fv -> rows 35..290 (packed)
        #pragma unroll
        for (int r = 0; r < 4; ++r)
          hb[(34 + j) * STR + colb + r] = pack_hl(a[r]);
      }
    }
  }
  __syncthreads();

  // ---------------- fine MLP ----------------
  layer<10, 16, 291>(hb, fW0p, fb0, p, kq, l, post_act);
  __syncthreads();
  layer<8, 16, 256>(hb, fW1p, fb1, p, kq, l, post_act);
  __syncthreads();

  {
    AF af[8];
    load_a<8, 256>(hb, p, kq, af);
    __syncthreads();
    float* hbf = (float*)hb;                  // epilogue staging is raw fp32
    const short8* __restrict__ wp0 = ((const short8*)fW2p) + (l << 1);
    #pragma unroll
    for (int n = 0; n < 17; ++n) {
      const int j = n * 16 + (l & 15);
      const float bv = (j < 257) ? fb2[j] : 0.0f;
      f32x4 a = {bv, bv, bv, bv};
      const short8* wp = wp0 + (size_t)(n * 8) * 128;
      #pragma unroll
      for (int t = 0; t < 8; ++t) {
        const short8 bh = wp[t * 128];
        const short8 bl = wp[t * 128 + 1];
        a = __builtin_amdgcn_mfma_f32_16x16x32_bf16(af[t].h, bh, a, 0, 0, 0);
        a = __builtin_amdgcn_mfma_f32_16x16x32_bf16(af[t].h, bl, a, 0, 0, 0);
        a = __builtin_amdgcn_mfma_f32_16x16x32_bf16(af[t].l, bh, a, 0, 0, 0);
      }
      if (j <= 256) {
        #pragma unroll
        for (int r = 0; r < 4; ++r)
          hbf[j * STR + colb + r] = ck[n][r] + a[r];
      }
    }
  }
  __syncthreads();

  // ---------------- transposed coalesced store ----------------
  const float* hbf = (const float*)hb;
  const size_t obase = (size_t)pbase * 257;
  for (int idx = tid; idx < NPB * 257; idx += 256) {
    const int pp = idx / 257;
    const int j = idx - pp * 257;
    out[obase + idx] = hbf[j * STR + pp];
  }
}

extern "C" void kernel_launch(void* const* d_in, const int* in_sizes, int n_in,
                              void* d_out, int out_size, void* d_ws, size_t ws_size,
                              hipStream_t stream) {
  (void)n_in; (void)out_size; (void)ws_size;
  // Replicate numpy's RES computation with host libm doubles.
  EncParams ep;
  const double sc = std::exp((std::log(2048.0) - std::log(16.0)) / 15.0);
  unsigned dm = 0;
  for (int l = 0; l < NLEV; ++l) {
    const int r = (int)std::ceil(16.0 * std::pow(sc, (double)l));
    ep.res[l] = r;
    const long long rp = (long long)r + 1;
    if (rp * rp * rp <= (long long)TBLSZ) dm |= (1u << l);
  }
  ep.dense_mask = dm;

  const float* X    = (const float*)d_in[0];
  const float* ctab = (const float*)d_in[1];
  const float* cW0  = (const float*)d_in[2];
  const float* cb0  = (const float*)d_in[3];
  const float* cW1  = (const float*)d_in[4];
  const float* cb1  = (const float*)d_in[5];
  const float* cW2  = (const float*)d_in[6];
  const float* cb2  = (const float*)d_in[7];
  const float* ftab = (const float*)d_in[8];
  const float* fW0  = (const float*)d_in[9];
  const float* fb0  = (const float*)d_in[10];
  const float* fW1  = (const float*)d_in[11];
  const float* fb1  = (const float*)d_in[12];
  const float* fW2  = (const float*)d_in[13];
  const float* fb2  = (const float*)d_in[14];

  u16* ws = (u16*)d_ws;                     // needs 1,474,560 bytes
  u16* cW0p = ws + 0;
  u16* cW1p = ws + 32768;
  u16* cW2p = ws + 163840;
  u16* fW0p = ws + 303104;
  u16* fW1p = ws + 466944;
  u16* fW2p = ws + 598016;

  prep_weights<<<dim3(1440), dim3(256), 0, stream>>>(cW0, cW1, cW2, fW0, fW1, fW2, ws);

  const int N = in_sizes[0] / 3;
  fused_ingp<<<dim3(N / NPB), dim3(256), 0, stream>>>(
      X, ctab, cb0, cb1, cb2, ftab, fb0, fb1, fb2,
      cW0p, cW1p, cW2p, fW0p, fW1p, fW2p,
      (float*)d_out, ep);
}

// Round 3
// 2184.384 us; speedup vs baseline: 4.2247x; 1.0652x over previous
//
#include <hip/hip_runtime.h>
#include <cmath>

#define NLEV 16
#define TBLSZ 524288
#define TMASK 524287u
#define STR 66           // LDS row stride in u32; (66 mod 32)=2 -> tile patterns <=2-way (free-ish)
#define ROWS 291         // max activation rows (fine MLP input)
#define NPB 64           // points per block

typedef short short8 __attribute__((ext_vector_type(8)));
typedef float f32x4 __attribute__((ext_vector_type(4)));
typedef unsigned int u32;
typedef unsigned short u16;

struct EncParams { int res[NLEV]; unsigned dense_mask; };

__device__ __host__ __forceinline__ u32 bf16_rtne_bits(float x) {
  union { float f; u32 u; } c; c.f = x;
  return (c.u + 0x7fffu + ((c.u >> 16) & 1u)) >> 16;
}

__device__ __forceinline__ float softplus100(float x) {
  float t = 100.0f * x;
  return (fmaxf(t, 0.0f) + log1pf(expf(-fabsf(t)))) * 0.01f;
}

// pack fp32 -> (hi bf16) | (lo bf16 << 16), hi+lo ~= x to ~2^-17 rel.
__device__ __forceinline__ u32 pack_hl(float x) {
  u32 hi = bf16_rtne_bits(x);
  float r = x - __uint_as_float(hi << 16);
  u32 lo = bf16_rtne_bits(r);
  return hi | (lo << 16);
}
// unpack: hi = low16<<16, lo = high16 bits as-is.
__device__ __forceinline__ float unpack_hl(u32 v) {
  return __uint_as_float(v << 16) + __uint_as_float(v & 0xFFFF0000u);
}

struct AF { short8 h, l; };

// Load A-fragments (activations) for all K-tiles of a layer from packed LDS.
// lane l supplies A[row = l&15][k = kq + e] per MFMA; p = point column in LDS.
template<int KT, int IN>
__device__ __forceinline__ void load_a(const u32* hb, int p, int kq, AF* af) {
  #pragma unroll
  for (int t = 0; t < KT; ++t) {
    u32 pk[8];
    const bool tail = ((t + 1) * 32 > IN);   // compile-time after unroll
    #pragma unroll
    for (int e = 0; e < 8; ++e) {
      const int k = t * 32 + kq + e;
      if (tail) {
        const int row = (k < IN) ? k : (IN - 1);     // stay in-bounds
        const u32 v = hb[row * STR + p];
        pk[e] = (k < IN) ? v : 0u;                   // NaN-guard padding lanes
      } else {
        pk[e] = hb[k * STR + p];
      }
    }
    union { u32 u[4]; short8 v; } ch, cl;
    #pragma unroll
    for (int q = 0; q < 4; ++q) {
      ch.u[q] = __builtin_amdgcn_perm(pk[2 * q + 1], pk[2 * q], 0x05040100u); // low16s
      cl.u[q] = __builtin_amdgcn_perm(pk[2 * q + 1], pk[2 * q], 0x07060302u); // high16s
    }
    af[t].h = ch.v;
    af[t].l = cl.v;
  }
}

// 2Mx2N layer: wave owns M=32 (A-tiles at p0, p0+16) x N=NTW*16 (n-tiles nbase..).
// Each B fragment pair (bh,bl) feeds 6 MFMAs (2 M-tiles x 3 split-bf16 terms).
template<int KT, int NTW, int IN, class Post>
__device__ __forceinline__ void layer2(const u32* __restrict__ hb,
                                       const u16* __restrict__ wf,
                                       const float* __restrict__ bias,
                                       int nbase, int p0, int kq, int l, Post&& post) {
  AF a0[KT], a1[KT];
  load_a<KT, IN>(hb, p0, kq, a0);
  load_a<KT, IN>(hb, p0 + 16, kq, a1);
  __syncthreads();                         // everyone's A in regs -> LDS rows writable
  const short8* __restrict__ wp0 = ((const short8*)wf) + (l << 1);
  #pragma unroll 2
  for (int n = 0; n < NTW; ++n) {
    const int nn = nbase + n;
    const int j = nn * 16 + (l & 15);
    const float bv = bias[j];
    f32x4 acc0 = {bv, bv, bv, bv}, acc1 = acc0;
    const short8* wp = wp0 + (size_t)(nn * KT) * 128;
    #pragma unroll
    for (int t = 0; t < KT; ++t) {
      const short8 bh = wp[t * 128];
      const short8 bl = wp[t * 128 + 1];
      acc0 = __builtin_amdgcn_mfma_f32_16x16x32_bf16(a0[t].h, bh, acc0, 0, 0, 0);
      acc1 = __builtin_amdgcn_mfma_f32_16x16x32_bf16(a1[t].h, bh, acc1, 0, 0, 0);
      acc0 = __builtin_amdgcn_mfma_f32_16x16x32_bf16(a0[t].h, bl, acc0, 0, 0, 0);
      acc1 = __builtin_amdgcn_mfma_f32_16x16x32_bf16(a1[t].h, bl, acc1, 0, 0, 0);
      acc0 = __builtin_amdgcn_mfma_f32_16x16x32_bf16(a0[t].l, bh, acc0, 0, 0, 0);
      acc1 = __builtin_amdgcn_mfma_f32_16x16x32_bf16(a1[t].l, bh, acc1, 0, 0, 0);
    }
    post(j, acc0, acc1);
  }
}

// ---------------- weight prep: fp32 [O x K] -> hi/lo bf16 B-fragments ----------------
__global__ __launch_bounds__(256)
void prep_weights(const float* __restrict__ s0, const float* __restrict__ s1,
                  const float* __restrict__ s2, const float* __restrict__ s3,
                  const float* __restrict__ s4, const float* __restrict__ s5,
                  u16* __restrict__ ws) {
  const int O[6]   = {256, 256, 257, 256, 256, 257};
  const int K[6]   = {35, 256, 256, 291, 256, 256};
  const int KT[6]  = {2, 8, 8, 10, 8, 8};
  const int NE[6]  = {16384, 65536, 69632, 81920, 65536, 69632};     // Opad*Kpad elements
  const int OFF[6] = {0, 32768, 163840, 303104, 466944, 598016};     // u16 offsets (2*NE cum.)
  const float* S[6] = {s0, s1, s2, s3, s4, s5};
  int t = blockIdx.x * 256 + threadIdx.x;
  #pragma unroll
  for (int L = 0; L < 6; ++L) {
    if (t < NE[L]) {
      const int e = t & 7, lane = (t >> 3) & 63, f = t >> 9;
      const int kt = f % KT[L], nt = f / KT[L];
      const int j = nt * 16 + (lane & 15);
      const int k = kt * 32 + ((lane >> 4) << 3) + e;
      const float v = (j < O[L] && k < K[L]) ? S[L][(size_t)j * K[L] + k] : 0.0f;
      const u32 hi = bf16_rtne_bits(v);
      const float r = v - __uint_as_float(hi << 16);
      const u32 lo = bf16_rtne_bits(r);
      // fragment stride 1024 u16, lane stride 16 u16 (matches consumer addressing)
      u16* d = ws + OFF[L] + (size_t)f * 1024 + (size_t)lane * 16;
      d[e] = (u16)hi;
      d[8 + e] = (u16)lo;
      return;
    }
    t -= NE[L];
  }
}

// ---------------- fused kernel ----------------
__global__ __launch_bounds__(256, 2)
void fused_ingp(const float* __restrict__ x,
                const float* __restrict__ ctab, const float* __restrict__ cb0,
                const float* __restrict__ cb1, const float* __restrict__ cb2,
                const float* __restrict__ ftab, const float* __restrict__ fb0,
                const float* __restrict__ fb1, const float* __restrict__ fb2,
                const u16* __restrict__ cW0p, const u16* __restrict__ cW1p,
                const u16* __restrict__ cW2p, const u16* __restrict__ fW0p,
                const u16* __restrict__ fW1p, const u16* __restrict__ fW2p,
                float* __restrict__ out, EncParams ep) {
  __shared__ u32 hb[ROWS * STR];           // packed hi/lo bf16 activations (u32 each)
  const int tid = threadIdx.x;
  const int l = tid & 63;
  const int g = __builtin_amdgcn_readfirstlane(tid >> 6);
  const int mg = g & 1;                     // M-half: points [mg*32, mg*32+32)
  const int ng = g >> 1;                    // N-half
  const int pbase = blockIdx.x * NPB;
  const int pt = pbase + l;
  const int p0 = mg * 32 + (l & 15);        // A-read point column (tile 0; tile 1 = +16)
  const int kq = (l >> 4) << 3;             // k-group within K-tile
  const int cb = mg * 32 + ((l >> 4) << 2); // D-write point column base (tile 0; tile 1 = +16)

  // ------------- hash encode: 4 levels per wave, both tables share idx/weights -------------
  const float* xp = x + (size_t)3 * pt;
  const float x0 = xp[0], x1 = xp[1], x2 = xp[2];
  const float q0 = fminf(fmaxf((x0 / 1.5f + 1.0f) * 0.5f, 0.0f), 1.0f);
  const float q1 = fminf(fmaxf((x1 / 1.5f + 1.0f) * 0.5f, 0.0f), 1.0f);
  const float q2 = fminf(fmaxf((x2 / 1.5f + 1.0f) * 0.5f, 0.0f), 1.0f);

  if (g == 0) {
    const u32 px0 = pack_hl(x0), px1 = pack_hl(x1), px2 = pack_hl(x2);
    hb[0 * STR + l] = px0; hb[1 * STR + l] = px1; hb[2 * STR + l] = px2;
    hb[288 * STR + l] = px0; hb[289 * STR + l] = px1; hb[290 * STR + l] = px2;
  }

  #pragma unroll
  for (int il = 0; il < 4; ++il) {
    const int lv = g * 4 + il;
    const int res = ep.res[lv];
    const bool dense = (ep.dense_mask >> lv) & 1;
    const float rf = (float)(res - 1);
    const float px = q0 * rf, py = q1 * rf, pz = q2 * rf;
    const int ix = (int)floorf(px), iy = (int)floorf(py), iz = (int)floorf(pz);
    const float wx = px - (float)ix, wy = py - (float)iy, wz = pz - (float)iz;
    float ca0 = 0.f, ca1 = 0.f, fa0 = 0.f, fa1 = 0.f;
    const float* ct = ctab + (size_t)lv * TBLSZ * 2;
    const float* ft = ftab + (size_t)lv * TBLSZ * 2;
    #pragma unroll
    for (int c = 0; c < 8; ++c) {
      const int ox = c & 1, oy = (c >> 1) & 1, oz = (c >> 2) & 1;
      const int cx = min(ix + ox, res), cy = min(iy + oy, res), cz = min(iz + oz, res);
      unsigned idx;
      if (dense) idx = (unsigned)(cx + (res + 1) * (cy + (res + 1) * cz));
      else idx = (((unsigned)cx) ^ ((unsigned)cy * 2654435761u) ^ ((unsigned)cz * 805459861u)) & TMASK;
      const float wc = (ox ? wx : 1.0f - wx) * (oy ? wy : 1.0f - wy) * (oz ? wz : 1.0f - wz);
      const float2 cv = *(const float2*)(ct + (size_t)idx * 2);
      const float2 fv = *(const float2*)(ft + (size_t)idx * 2);
      ca0 = fmaf(wc, cv.x, ca0); ca1 = fmaf(wc, cv.y, ca1);
      fa0 = fmaf(wc, fv.x, fa0); fa1 = fmaf(wc, fv.y, fa1);
    }
    hb[(3 + 2 * lv) * STR + l] = pack_hl(ca0);    // c_feat -> rows 3..34
    hb[(4 + 2 * lv) * STR + l] = pack_hl(ca1);
    hb[(256 + 2 * lv) * STR + l] = pack_hl(fa0);  // f_feat stash rows 256..287
    hb[(257 + 2 * lv) * STR + l] = pack_hl(fa1);
  }
  __syncthreads();

  auto post_act = [&](int j, f32x4 a0, f32x4 a1) {
    #pragma unroll
    for (int r = 0; r < 4; ++r) {
      hb[j * STR + cb + r]      = pack_hl(softplus100(a0[r]));
      hb[j * STR + cb + 16 + r] = pack_hl(softplus100(a1[r]));
    }
  };

  // ---------------- coarse MLP ----------------
  layer2<2, 8, 35>(hb, cW0p, cb0, ng * 8, p0, kq, l, post_act);
  __syncthreads();
  layer2<8, 8, 256>(hb, cW1p, cb1, ng * 8, p0, kq, l, post_act);
  __syncthreads();

  // ---------------- coarse L2: c_out -> global stash (packed) + c_fv -> LDS ----------------
  u32* __restrict__ out_u = (u32*)out;
  {
    AF a0[8], a1[8];
    load_a<8, 256>(hb, p0, kq, a0);
    load_a<8, 256>(hb, p0 + 16, kq, a1);
    __syncthreads();
    // stash copy-down: rows 288..290 -> 0..2 (x), 256..287 -> 3..34 (f_feat)
    for (int r = g; r < 35; r += 4) {
      const int src = (r < 3) ? (288 + r) : (253 + r);
      hb[r * STR + l] = hb[src * STR + l];
    }
    __syncthreads();
    const short8* __restrict__ wp0 = ((const short8*)cW2p) + (l << 1);
    const int NTW = ng ? 8 : 9, nb = ng ? 9 : 0;
    for (int n = 0; n < NTW; ++n) {
      const int nn = nb + n;
      const int j = nn * 16 + (l & 15);
      const float bv = (j < 257) ? cb2[j] : 0.0f;
      f32x4 acc0 = {bv, bv, bv, bv}, acc1 = acc0;
      const short8* wp = wp0 + (size_t)(nn * 8) * 128;
      #pragma unroll
      for (int t = 0; t < 8; ++t) {
        const short8 bh = wp[t * 128];
        const short8 bl = wp[t * 128 + 1];
        acc0 = __builtin_amdgcn_mfma_f32_16x16x32_bf16(a0[t].h, bh, acc0, 0, 0, 0);
        acc1 = __builtin_amdgcn_mfma_f32_16x16x32_bf16(a1[t].h, bh, acc1, 0, 0, 0);
        acc0 = __builtin_amdgcn_mfma_f32_16x16x32_bf16(a0[t].h, bl, acc0, 0, 0, 0);
        acc1 = __builtin_amdgcn_mfma_f32_16x16x32_bf16(a1[t].h, bl, acc1, 0, 0, 0);
        acc0 = __builtin_amdgcn_mfma_f32_16x16x32_bf16(a0[t].l, bh, acc0, 0, 0, 0);
        acc1 = __builtin_amdgcn_mfma_f32_16x16x32_bf16(a1[t].l, bh, acc1, 0, 0, 0);
      }
      if (j <= 256) {
        #pragma unroll
        for (int r = 0; r < 4; ++r) {
          const u32 v0 = pack_hl(acc0[r]);
          const u32 v1 = pack_hl(acc1[r]);
          // c_out stash (packed hi/lo) into the output buffer; overwritten at epilogue
          __builtin_nontemporal_store(v0, &out_u[(size_t)(pbase + cb + r) * 257 + j]);
          __builtin_nontemporal_store(v1, &out_u[(size_t)(pbase + cb + 16 + r) * 257 + j]);
          if (j >= 1) {                       // c_fv -> rows 35..290 (packed)
            hb[(34 + j) * STR + cb + r]      = v0;
            hb[(34 + j) * STR + cb + 16 + r] = v1;
          }
        }
      }
    }
  }
  __syncthreads();

  // ---------------- fine MLP ----------------
  layer2<10, 8, 291>(hb, fW0p, fb0, ng * 8, p0, kq, l, post_act);
  __syncthreads();
  layer2<8, 8, 256>(hb, fW1p, fb1, ng * 8, p0, kq, l, post_act);
  __syncthreads();

  // ---------------- fine L2: f_out -> LDS (f32) ----------------
  {
    AF a0[8], a1[8];
    load_a<8, 256>(hb, p0, kq, a0);
    load_a<8, 256>(hb, p0 + 16, kq, a1);
    __syncthreads();
    float* hbf = (float*)hb;
    const short8* __restrict__ wp0 = ((const short8*)fW2p) + (l << 1);
    const int NTW = ng ? 8 : 9, nb = ng ? 9 : 0;
    for (int n = 0; n < NTW; ++n) {
      const int nn = nb + n;
      const int j = nn * 16 + (l & 15);
      const float bv = (j < 257) ? fb2[j] : 0.0f;
      f32x4 acc0 = {bv, bv, bv, bv}, acc1 = acc0;
      const short8* wp = wp0 + (size_t)(nn * 8) * 128;
      #pragma unroll
      for (int t = 0; t < 8; ++t) {
        const short8 bh = wp[t * 128];
        const short8 bl = wp[t * 128 + 1];
        acc0 = __builtin_amdgcn_mfma_f32_16x16x32_bf16(a0[t].h, bh, acc0, 0, 0, 0);
        acc1 = __builtin_amdgcn_mfma_f32_16x16x32_bf16(a1[t].h, bh, acc1, 0, 0, 0);
        acc0 = __builtin_amdgcn_mfma_f32_16x16x32_bf16(a0[t].h, bl, acc0, 0, 0, 0);
        acc1 = __builtin_amdgcn_mfma_f32_16x16x32_bf16(a1[t].h, bl, acc1, 0, 0, 0);
        acc0 = __builtin_amdgcn_mfma_f32_16x16x32_bf16(a0[t].l, bh, acc0, 0, 0, 0);
        acc1 = __builtin_amdgcn_mfma_f32_16x16x32_bf16(a1[t].l, bh, acc1, 0, 0, 0);
      }
      if (j <= 256) {
        #pragma unroll
        for (int r = 0; r < 4; ++r) {
          hbf[j * STR + cb + r]      = acc0[r];
          hbf[j * STR + cb + 16 + r] = acc1[r];
        }
      }
    }
  }
  __syncthreads();

  // ---------------- epilogue: out = unpack(c_stash) + f, coalesced RMW ----------------
  const float* hbf = (const float*)hb;
  const size_t obase = (size_t)pbase * 257;
  for (int idx = tid; idx < NPB * 257; idx += 256) {
    const int pp = idx / 257;
    const int j = idx - pp * 257;
    const u32 cpk = __builtin_nontemporal_load(&out_u[obase + idx]);
    out[obase + idx] = unpack_hl(cpk) + hbf[j * STR + pp];
  }
}

extern "C" void kernel_launch(void* const* d_in, const int* in_sizes, int n_in,
                              void* d_out, int out_size, void* d_ws, size_t ws_size,
                              hipStream_t stream) {
  (void)n_in; (void)out_size; (void)ws_size;
  // Replicate numpy's RES computation with host libm doubles.
  EncParams ep;
  const double sc = std::exp((std::log(2048.0) - std::log(16.0)) / 15.0);
  unsigned dm = 0;
  for (int l = 0; l < NLEV; ++l) {
    const int r = (int)std::ceil(16.0 * std::pow(sc, (double)l));
    ep.res[l] = r;
    const long long rp = (long long)r + 1;
    if (rp * rp * rp <= (long long)TBLSZ) dm |= (1u << l);
  }
  ep.dense_mask = dm;

  const float* X    = (const float*)d_in[0];
  const float* ctab = (const float*)d_in[1];
  const float* cW0  = (const float*)d_in[2];
  const float* cb0  = (const float*)d_in[3];
  const float* cW1  = (const float*)d_in[4];
  const float* cb1  = (const float*)d_in[5];
  const float* cW2  = (const float*)d_in[6];
  const float* cb2  = (const float*)d_in[7];
  const float* ftab = (const float*)d_in[8];
  const float* fW0  = (const float*)d_in[9];
  const float* fb0  = (const float*)d_in[10];
  const float* fW1  = (const float*)d_in[11];
  const float* fb1  = (const float*)d_in[12];
  const float* fW2  = (const float*)d_in[13];
  const float* fb2  = (const float*)d_in[14];

  u16* ws = (u16*)d_ws;                     // needs 1,474,560 bytes
  u16* cW0p = ws + 0;
  u16* cW1p = ws + 32768;
  u16* cW2p = ws + 163840;
  u16* fW0p = ws + 303104;
  u16* fW1p = ws + 466944;
  u16* fW2p = ws + 598016;

  prep_weights<<<dim3(1440), dim3(256), 0, stream>>>(cW0, cW1, cW2, fW0, fW1, fW2, ws);

  const int N = in_sizes[0] / 3;
  fused_ingp<<<dim3(N / NPB), dim3(256), 0, stream>>>(
      X, ctab, cb0, cb1, cb2, ftab, fb0, fb1, fb2,
      cW0p, cW1p, cW2p, fW0p, fW1p, fW2p,
      (float*)d_out, ep);
}